// Round 4
// baseline (8475.425 us; speedup 1.0000x reference)
//
#include <hip/hip_runtime.h>
#include <hip/hip_fp16.h>
#include <cstddef>

#define T_LEN 4096
#define HID 150
#define G4 600
#define NC 300

typedef __attribute__((ext_vector_type(8))) short bf16x8;      // 8 bf16 = 4 VGPRs
typedef __attribute__((ext_vector_type(8))) _Float16 f16x8;    // 8 fp16 = 4 VGPRs
typedef __attribute__((ext_vector_type(4))) float f32x4;

// raw barrier: waits LDS ops only, leaves global loads/stores in flight
__device__ __forceinline__ void barrier_lgkm() {
  asm volatile("s_waitcnt lgkmcnt(0)\n\ts_barrier" ::: "memory");
}

__device__ __forceinline__ float fsig(float x) {
  return __builtin_amdgcn_rcpf(1.f + __expf(-x));
}
__device__ __forceinline__ float ftanh(float x) {
  float ax = fabsf(x);
  float e = __expf(2.f * ax);
  float t = 1.f - 2.f * __builtin_amdgcn_rcpf(e + 1.f);
  return copysignf(t, x);
}
__device__ __forceinline__ unsigned short f2bf(float f) {  // RNE fp32->bf16
  unsigned u = __builtin_bit_cast(unsigned, f);
  u += 0x7fff + ((u >> 16) & 1);
  return (unsigned short)(u >> 16);
}

// ---------------- LSTM scan via MFMA (r12 = r11 + prefetch distance 2) ---------
// HISTORY (cyc/step): r3 two-phase=1743; r5 af-hoist=1854; r6 gate-permute=2439;
// r7 16-wave=1968; r8 1-barrier=1893; r9 bcast-B+select=2361; r10 gate-major
// 10-wave=2231; r11 (gate-interleaved g4 + b128 gate read + running ptrs)=1780
// BEST. LAW: two-phase + 8 waves + gate work on 3 waves; barriers not the
// bottleneck (r8/r9/r10). r12 theory: xg rows are streaming HBM misses
// (FETCH~=35MB=all of xg); 1-step prefetch slack (~600cyc) < HBM latency
// (~900cyc) -> ~300cyc vmcnt stall/step on gate waves. Fix: distance-2
// prefetch via x2 unroll + xrA/xrB ping-pong (slack ~3500cyc).
template <int W32>
__global__ __launch_bounds__(512, 2) void lstm_scan(
    const float* __restrict__ whh_solv, const float* __restrict__ whh_solu,
    const float* __restrict__ xg_base,
    float* __restrict__ o32v, float* __restrict__ o32u,
    __half* __restrict__ o16v, __half* __restrict__ o16u, int layer)
{
  __shared__ __align__(16) unsigned short h_bf[160];  // bf16 h, zeros beyond 150
  __shared__ __align__(16) float g4[160][4];          // unit-major, gate-minor
  const int c = blockIdx.x;
  const int net = c >> 1, dir = c & 1;
  const float* Whh = (net ? whh_solu : whh_solv) + (size_t)(layer * 2 + dir) * (G4 * HID);
  const float* xg = xg_base + (size_t)c * T_LEN * G4;
  float* out32 = (net ? o32u : o32v) + dir * HID;     // row stride NC (if W32)
  __half* out16 = (net ? o16u : o16v) + dir * HID;    // row stride 320
  const int tid = threadIdx.x;
  const int lane = tid & 63, wv = tid >> 6;
  const int lrow = lane & 15, lq = lane >> 4;  // frag row & k-quad

  // B-fragments, gate-interleaved tiles: T=wv+8j, gt=T&3, uw=T>>2.
  // B[k][lrow] = Whh[gt*150 + (16*uw+lrow)][k]; zero-padded.
  bf16x8 bfr[5][5];  // [j][kk]
#pragma unroll
  for (int j = 0; j < 5; j++) {
    const int T = wv + 8 * j, gt = T & 3, uw = T >> 2;
    const int un = 16 * uw + lrow;
#pragma unroll
    for (int kk = 0; kk < 5; kk++) {
      bf16x8 b;
#pragma unroll
      for (int i = 0; i < 8; i++) {
        const int k = kk * 32 + lq * 8 + i;
        const float v = (un < HID && k < HID) ? Whh[(size_t)(gt * HID + un) * HID + k] : 0.f;
        b[i] = (short)f2bf(v);
      }
      bfr[j][kk] = b;
    }
  }
  if (tid < 160) h_bf[tid] = 0;

  const int t0 = dir ? (T_LEN - 1) : 0;
  const int d16 = dir ? -320 : 320;
  const int d32 = dir ? -NC : NC;
  const int dxg = dir ? -G4 : G4;
  float cst = 0.f;
  // ping-pong xg prefetch, distance 2: xrA holds rows t0, t0+2d, ...; xrB odd rows
  float xa0 = 0.f, xa1 = 0.f, xa2 = 0.f, xa3 = 0.f;
  float xb0 = 0.f, xb1 = 0.f, xb2 = 0.f, xb3 = 0.f;
  const float* xgpA = xg + (size_t)t0 * G4 + tid;   // gate lanes only
  const float* xgpB = xgpA + dxg;
  __half* o16p = out16 + (size_t)t0 * 320 + tid;
  float* o32p = out32 + (size_t)t0 * NC + tid;
  if (tid < HID) {
    xa0 = xgpA[0]; xa1 = xgpA[HID]; xa2 = xgpA[2 * HID]; xa3 = xgpA[3 * HID];
    xb0 = xgpB[0]; xb1 = xgpB[HID]; xb2 = xgpB[2 * HID]; xb3 = xgpB[3 * HID];
  }
  barrier_lgkm();

  for (int s = 0; s < T_LEN; s += 2) {
    // ================= body A (step s, consumes xrA, prefetches s+2) =========
    {
      bf16x8 af[5];
#pragma unroll
      for (int kk = 0; kk < 5; kk++) {
        bf16x8 a = {0, 0, 0, 0, 0, 0, 0, 0};
        if (lrow == 0) a = *(const bf16x8*)&h_bf[kk * 32 + lq * 8];
        af[kk] = a;
      }
      f32x4 acc[5];
#pragma unroll
      for (int j = 0; j < 5; j++) acc[j] = (f32x4){0.f, 0.f, 0.f, 0.f};
#pragma unroll
      for (int kk = 0; kk < 5; kk++)
#pragma unroll
        for (int j = 0; j < 5; j++)
          acc[j] = __builtin_amdgcn_mfma_f32_16x16x32_bf16(af[kk], bfr[j][kk], acc[j], 0, 0, 0);
      if (lane < 16) {
#pragma unroll
        for (int j = 0; j < 5; j++) {
          const int T = wv + 8 * j, gt = T & 3, uw = T >> 2;
          g4[16 * uw + lane][gt] = acc[j][0];
        }
      }
      barrier_lgkm();
      if (tid < HID) {
        const f32x4 g = *(const f32x4*)&g4[tid][0];   // ONE b128, coalesced
        float gi = xa0 + g[0];
        float gf = xa1 + g[1];
        float gg = xa2 + g[2];
        float go = xa3 + g[3];
        xgpA += 2 * dxg;
        if (s + 2 < T_LEN) {  // prefetch row s+2 (2-step slack > HBM latency)
          xa0 = xgpA[0]; xa1 = xgpA[HID]; xa2 = xgpA[2 * HID]; xa3 = xgpA[3 * HID];
        }
        const float iv = fsig(gi), fv = fsig(gf), gv = ftanh(gg), ov = fsig(go);
        cst = fv * cst + iv * gv;
        const float hv = ov * ftanh(cst);
        h_bf[tid] = f2bf(hv);      // matvec input rounded; c/h state stays fp32
        *o16p = __float2half(hv);
        o16p += d16;
        if (W32) { *o32p = hv; o32p += d32; }
      }
      barrier_lgkm();
    }
    // ================= body B (step s+1, consumes xrB, prefetches s+3) =======
    {
      bf16x8 af[5];
#pragma unroll
      for (int kk = 0; kk < 5; kk++) {
        bf16x8 a = {0, 0, 0, 0, 0, 0, 0, 0};
        if (lrow == 0) a = *(const bf16x8*)&h_bf[kk * 32 + lq * 8];
        af[kk] = a;
      }
      f32x4 acc[5];
#pragma unroll
      for (int j = 0; j < 5; j++) acc[j] = (f32x4){0.f, 0.f, 0.f, 0.f};
#pragma unroll
      for (int kk = 0; kk < 5; kk++)
#pragma unroll
        for (int j = 0; j < 5; j++)
          acc[j] = __builtin_amdgcn_mfma_f32_16x16x32_bf16(af[kk], bfr[j][kk], acc[j], 0, 0, 0);
      if (lane < 16) {
#pragma unroll
        for (int j = 0; j < 5; j++) {
          const int T = wv + 8 * j, gt = T & 3, uw = T >> 2;
          g4[16 * uw + lane][gt] = acc[j][0];
        }
      }
      barrier_lgkm();
      if (tid < HID) {
        const f32x4 g = *(const f32x4*)&g4[tid][0];
        float gi = xb0 + g[0];
        float gf = xb1 + g[1];
        float gg = xb2 + g[2];
        float go = xb3 + g[3];
        xgpB += 2 * dxg;
        if (s + 3 < T_LEN) {  // prefetch row s+3
          xb0 = xgpB[0]; xb1 = xgpB[HID]; xb2 = xgpB[2 * HID]; xb3 = xgpB[3 * HID];
        }
        const float iv = fsig(gi), fv = fsig(gf), gv = ftanh(gg), ov = fsig(go);
        cst = fv * cst + iv * gv;
        const float hv = ov * ftanh(cst);
        h_bf[tid] = f2bf(hv);
        *o16p = __float2half(hv);
        o16p += d16;
        if (W32) { *o32p = hv; o32p += d32; }
      }
      barrier_lgkm();
    }
  }
}

// ---------------- fp32 -> fp16 conversion helpers ------------------------------
// Wihh[8][640][320]: slot s = l*4 + net*2 + dir, zero-padded rows/cols
__global__ void conv_w(const float* __restrict__ wv, const float* __restrict__ wu,
                       __half* __restrict__ dst)
{
  const int gid = blockIdx.x * 256 + threadIdx.x;
  if (gid >= 8 * 640 * 320) return;
  const int k = gid % 320, j = (gid / 320) % 640, s = gid / (320 * 640);
  const int l = s >> 2, net = (s >> 1) & 1, dir = s & 1;
  float v = 0.f;
  if (j < G4 && k < NC) {
    const float* src = (net ? wu : wv) + (size_t)(l * 2 + dir) * (G4 * NC);
    v = src[(size_t)j * NC + k];
  }
  dst[gid] = __float2half(v);
}

// X fp32 [rows][300] -> Xh fp16 [rows][320] zero-padded
__global__ void conv_x(const float* __restrict__ src, __half* __restrict__ dst, int rows)
{
  const int gid = blockIdx.x * 256 + threadIdx.x;
  if (gid >= rows * 320) return;
  const int k = gid % 320, m = gid / 320;
  dst[gid] = __float2half(k < NC ? src[(size_t)m * NC + k] : 0.f);
}

// X fp32 [4096][300] -> XT fp16 [320][4096] (rows >= 300 zeroed)
__global__ void conv_t(const float* __restrict__ src, __half* __restrict__ dst)
{
  const int gid = blockIdx.x * 256 + threadIdx.x;
  if (gid >= 320 * 4096) return;
  const int m = gid % 4096, f = gid / 4096;
  dst[gid] = __float2half(f < NC ? src[(size_t)m * NC + f] : 0.f);
}

__global__ void zero_f(float* __restrict__ p, int n) {
  const int i = blockIdx.x * 256 + threadIdx.x;
  if (i < n) p[i] = 0.f;
}

// ---------------- xg = X @ Wih^T + b via fp16 MFMA -----------------------------
// grid (64 m-blocks, 4 chains), block 256 (4 waves, 16 rows each). N=640, K=320.
__global__ __launch_bounds__(256) void xg_mfma(
    const __half* __restrict__ Av, const __half* __restrict__ Au,
    const __half* __restrict__ W,   // Wihh + layer*4*640*320
    const float* __restrict__ bihv, const float* __restrict__ bhhv,
    const float* __restrict__ bihu, const float* __restrict__ bhhu,
    float* __restrict__ xg, int layer)
{
  const int tid = threadIdx.x;
  const int lane = tid & 63, wv = tid >> 6;
  const int ln = lane & 15, q = lane >> 4;
  const int chain = blockIdx.y;
  const __half* A = (chain >= 2) ? Au : Av;
  const __half* Wc = W + (size_t)chain * 640 * 320;
  const float* bi = ((chain >= 2) ? bihu : bihv) + (size_t)(layer * 2 + (chain & 1)) * G4;
  const float* bh = ((chain >= 2) ? bhhu : bhhv) + (size_t)(layer * 2 + (chain & 1)) * G4;
  float* C = xg + (size_t)chain * T_LEN * G4;
  const int m0 = blockIdx.x * 64 + wv * 16;
  const __half* Arow = A + (size_t)(m0 + ln) * 320;

  for (int nc = 0; nc < 4; nc++) {       // 4 chunks x 160 cols
    f32x4 acc[10];
#pragma unroll
    for (int j = 0; j < 10; j++) acc[j] = (f32x4){0.f, 0.f, 0.f, 0.f};
    for (int kk = 0; kk < 10; kk++) {
      const f16x8 afr = *(const f16x8*)(Arow + kk * 32 + q * 8);
#pragma unroll
      for (int j = 0; j < 10; j++) {
        const int n = nc * 160 + j * 16 + ln;
        const f16x8 bfr = *(const f16x8*)(Wc + (size_t)n * 320 + kk * 32 + q * 8);
        acc[j] = __builtin_amdgcn_mfma_f32_16x16x32_f16(afr, bfr, acc[j], 0, 0, 0);
      }
    }
#pragma unroll
    for (int j = 0; j < 10; j++) {
      const int n = nc * 160 + j * 16 + ln;
      if (n < G4) {
        const float bias = bi[n] + bh[n];
#pragma unroll
        for (int r = 0; r < 4; r++)
          C[(size_t)(m0 + q * 4 + r) * G4 + n] = acc[j][r] + bias;
      }
    }
  }
}

// ------- S GEMM: AH[m][n] = fp16(Hh[m] . Gh[n]), raw scores (no exp) -----------
// grid (64 m-blocks, 4 n-quadrants), block 256. Softmax shift/normalization
// happens later on the ROUNDED values (self-consistent).
__global__ __launch_bounds__(256) void s_gemm(
    const __half* __restrict__ Hh, const __half* __restrict__ Gh,
    __half* __restrict__ AH)
{
  const int tid = threadIdx.x;
  const int lane = tid & 63, wv = tid >> 6;
  const int ln = lane & 15, q = lane >> 4;
  const int m0 = blockIdx.x * 64 + wv * 16;
  const __half* Arow = Hh + (size_t)(m0 + ln) * 320;
  f16x8 afr[10];
#pragma unroll
  for (int kk = 0; kk < 10; kk++) afr[kk] = *(const f16x8*)(Arow + kk * 32 + q * 8);
  const int nt0 = blockIdx.y * 64;
  for (int nt = 0; nt < 64; nt++) {
    const int n = 16 * (nt0 + nt) + ln;
    const __half* Brow = Gh + (size_t)n * 320;
    f32x4 acc = (f32x4){0.f, 0.f, 0.f, 0.f};
#pragma unroll
    for (int kk = 0; kk < 10; kk++) {
      const f16x8 bfr = *(const f16x8*)(Brow + kk * 32 + q * 8);
      acc = __builtin_amdgcn_mfma_f32_16x16x32_f16(afr[kk], bfr, acc, 0, 0, 0);
    }
#pragma unroll
    for (int r = 0; r < 4; r++)
      AH[(size_t)(m0 + q * 4 + r) * 4096 + n] = __float2half(acc[r]);
  }
}

// ------- rowsum: il[m] = 1 / sum_n exp(S[m][n] - 30)  (one block per row) ------
__global__ __launch_bounds__(256) void rowsum_k(const __half* __restrict__ AH,
                                                float* __restrict__ il)
{
  const int m = blockIdx.x, tid = threadIdx.x;
  const __half* row = AH + (size_t)m * 4096;
  float s = 0.f;
  for (int i = tid * 8; i < 4096; i += 2048) {
    const f16x8 v = *(const f16x8*)(row + i);
#pragma unroll
    for (int j = 0; j < 8; j++) s += __expf(fminf((float)v[j] - 30.f, 80.f));
  }
#pragma unroll
  for (int off = 32; off > 0; off >>= 1) s += __shfl_down(s, off);
  __shared__ float red[4];
  if ((tid & 63) == 0) red[tid >> 6] = s;
  __syncthreads();
  if (tid == 0) il[m] = 1.f / (red[0] + red[1] + red[2] + red[3]);
}

// ------- scale: AH = fp16( exp(S-30) * il[m] ), in place -----------------------
__global__ __launch_bounds__(256) void scale_k(__half* __restrict__ AH,
                                               const float* __restrict__ il)
{
  const size_t gid = (size_t)blockIdx.x * 256 + threadIdx.x;  // f16x8 chunk id
  const int m = (int)(gid >> 9);                              // 512 chunks/row
  const float ilm = il[m];
  f16x8 v = *(f16x8*)(AH + gid * 8);
#pragma unroll
  for (int j = 0; j < 8; j++)
    v[j] = (_Float16)(__expf(fminf((float)v[j] - 30.f, 80.f)) * ilm);
  *(f16x8*)(AH + gid * 8) = v;
}

// ------- P = AH @ GhT' and Q = AH^T @ HhT' in ONE dispatch (128 blocks) --------
__global__ __launch_bounds__(256) void pq_mfma(
    const __half* __restrict__ AH, const __half* __restrict__ GhT,
    const __half* __restrict__ HhT,
    float* __restrict__ Pb, float* __restrict__ Qb)
{
  __shared__ __align__(16) _Float16 Ats[64][72];  // qt staging, pitch 144 B
  const int tid = threadIdx.x;
  const int lane = tid & 63, wv = tid >> 6;
  const int ln = lane & 15, q = lane >> 4;

  if (blockIdx.x < 64) {
    // ---- P part: M=4096 rows of AH, N=320(store 300), K=4096 ----
    const int m0 = blockIdx.x * 64 + wv * 16;
    const __half* Arow = AH + (size_t)(m0 + ln) * 4096;
    for (int nc = 0; nc < 2; nc++) {
      f32x4 acc[10];
#pragma unroll
      for (int j = 0; j < 10; j++) acc[j] = (f32x4){0.f, 0.f, 0.f, 0.f};
      for (int kk = 0; kk < 128; kk++) {
        const f16x8 afr = *(const f16x8*)(Arow + kk * 32 + q * 8);
#pragma unroll
        for (int j = 0; j < 10; j++) {
          const int n = nc * 160 + j * 16 + ln;
          const f16x8 bfr = *(const f16x8*)(GhT + (size_t)n * 4096 + kk * 32 + q * 8);
          acc[j] = __builtin_amdgcn_mfma_f32_16x16x32_f16(afr, bfr, acc[j], 0, 0, 0);
        }
      }
#pragma unroll
      for (int j = 0; j < 10; j++) {
        const int n = nc * 160 + j * 16 + ln;
        if (n < NC) {
#pragma unroll
          for (int r = 0; r < 4; r++)
            Pb[(size_t)(m0 + q * 4 + r) * NC + n] = acc[j][r];
        }
      }
    }
  } else {
    // ---- Q part: Q[j][f] = sum_i a[i][j] H[i][f]; a transposed via LDS ----
    const int j0 = (blockIdx.x - 64) * 64;
    f32x4 acc[20];
#pragma unroll
    for (int j = 0; j < 20; j++) acc[j] = (f32x4){0.f, 0.f, 0.f, 0.f};
    const int il8 = tid >> 2, j8 = (tid & 3) * 16;  // staging role
    for (int ic = 0; ic < 4096; ic += 64) {
      __syncthreads();
      {
        const __half* src = AH + (size_t)(ic + il8) * 4096 + j0 + j8;
        const f16x8 v0 = *(const f16x8*)src;
        const f16x8 v1 = *(const f16x8*)(src + 8);
#pragma unroll
        for (int jj = 0; jj < 8; jj++) Ats[j8 + jj][il8] = v0[jj];
#pragma unroll
        for (int jj = 0; jj < 8; jj++) Ats[j8 + 8 + jj][il8] = v1[jj];
      }
      __syncthreads();
#pragma unroll
      for (int s = 0; s < 2; s++) {
        const f16x8 afr = *(const f16x8*)&Ats[wv * 16 + ln][s * 32 + q * 8];
        const __half* bbase = HhT + ic + s * 32 + q * 8;
#pragma unroll
        for (int j = 0; j < 20; j++) {
          const f16x8 bfr = *(const f16x8*)(bbase + (size_t)(j * 16 + ln) * 4096);
          acc[j] = __builtin_amdgcn_mfma_f32_16x16x32_f16(afr, bfr, acc[j], 0, 0, 0);
        }
      }
    }
#pragma unroll
    for (int j = 0; j < 20; j++) {
      const int f = j * 16 + ln;
      if (f < NC) {
#pragma unroll
        for (int r = 0; r < 4; r++)
          Qb[(size_t)(j0 + wv * 16 + q * 4 + r) * NC + f] = acc[j][r];
      }
    }
  }
}

// ---------------- tail ---------------------------------------------------------
__global__ void reduce_uv(const float* __restrict__ X, const float* __restrict__ Yp,
                          float* __restrict__ inp, int off)
{
  const int j = threadIdx.x;
  if (j >= NC) return;
  const int r0 = blockIdx.x * 128;
  float s = 0.f;
  for (int r = r0; r < r0 + 128; r++)
    s += fmaxf(X[(size_t)r * NC + j], Yp[(size_t)r * NC + j]);
  atomicAdd(&inp[off + j], s);
}

__global__ void fc1_k(const float* __restrict__ w1, const float* __restrict__ b1,
                      const float* __restrict__ inp, float* __restrict__ x)
{
  const int r = blockIdx.x * 256 + threadIdx.x;
  if (r >= 2000) return;
  float s = b1[r];
  const float* wr = w1 + (size_t)r * 600;
  for (int k = 0; k < 600; k++) s += wr[k] * inp[k];
  x[r] = fmaxf(s, 0.f);
}

__global__ void fc2_k(const float* __restrict__ x, const float* __restrict__ w2,
                      const float* __restrict__ b2, float* __restrict__ outp)
{
  const int tid = threadIdx.x;
  float s = 0.f;
  for (int i = tid; i < 2000; i += 256) s += x[i] * w2[i];
#pragma unroll
  for (int off = 32; off > 0; off >>= 1) s += __shfl_down(s, off);
  __shared__ float red[4];
  if ((tid & 63) == 0) red[tid >> 6] = s;
  __syncthreads();
  if (tid == 0) outp[0] = red[0] + red[1] + red[2] + red[3] + b2[0];
}

// ---------------- launch --------------------------------------------------------
extern "C" void kernel_launch(void* const* d_in, const int* in_sizes, int n_in,
                              void* d_out, int out_size, void* d_ws, size_t ws_size,
                              hipStream_t stream)
{
  const float* in_solv  = (const float*)d_in[0];
  const float* in_solu  = (const float*)d_in[1];
  const float* solv_Wih = (const float*)d_in[2];
  const float* solv_Whh = (const float*)d_in[3];
  const float* solv_bih = (const float*)d_in[4];
  const float* solv_bhh = (const float*)d_in[5];
  const float* solu_Wih = (const float*)d_in[6];
  const float* solu_Whh = (const float*)d_in[7];
  const float* solu_bih = (const float*)d_in[8];
  const float* solu_bhh = (const float*)d_in[9];
  const float* fc1_w = (const float*)d_in[10];
  const float* fc1_b = (const float*)d_in[11];
  const float* fc2_w = (const float*)d_in[12];
  const float* fc2_b = (const float*)d_in[13];
  float* outp = (float*)d_out;
  float* ws = (float*)d_ws;

  // ---- workspace layout (float offsets); peak 16,067,200 fl < prior 17.2M ----
  // off_P:  Wihh (819,200 fl) early -> Pb fp32 late (Wihh dead after xg_mfma l1)
  // off_xg: xg (9,830,400 fl) -> AH fp16 (8,388,608 fl) + HhT/GhT (655,360 fl)
  // off_L0: Avh/Auh fp16 -> Hh/Gh fp16 (pads inherited from conv_x zeros)
  // off_HG: L0vh/L0uh fp16 (pads pre-zeroed) -> Hb/Gb fp32 (after xg_mfma l1)
  constexpr size_t off_P   = 0;
  constexpr size_t off_Q   = 1228800;
  constexpr size_t off_inp = 2457600;   // 640
  constexpr size_t off_x   = 2458240;   // 2048
  constexpr size_t off_il  = 2460288;   // 4096
  constexpr size_t off_xg  = 2468480;
  constexpr size_t off_L0  = off_xg + (size_t)4 * 2457600;   // 12,298,880
  constexpr size_t off_HG  = off_L0 + 1310720;               // 13,609,600

  float*  xg   = ws + off_xg;
  float*  Hb   = ws + off_HG;
  float*  Gb   = Hb + 1228800;
  float*  Pb   = ws + off_P;
  float*  Qb   = ws + off_Q;
  float*  inp  = ws + off_inp;
  float*  xf   = ws + off_x;
  float*  il   = ws + off_il;
  __half* Wihh = (__half*)(ws + off_P);
  __half* Avh  = (__half*)(ws + off_L0);
  __half* Auh  = Avh + 4096 * 320;
  __half* L0vh = (__half*)(ws + off_HG);
  __half* L0uh = L0vh + 4096 * 320;
  __half* Hh   = (__half*)(ws + off_L0);   // reuses Avh/Auh space (dead)
  __half* Gh   = Hh + 4096 * 320;
  __half* AH   = (__half*)(ws + off_xg);   // after scans (xg dead)
  __half* HhT  = AH + (size_t)4096 * 4096;
  __half* GhT  = HhT + 320 * 4096;

  // ---- prep: zero L0vh/L0uh pads, convert weights + inputs to fp16 ----
  zero_f<<<5120, 256, 0, stream>>>(ws + off_HG, 1310720);
  conv_w<<<(8 * 640 * 320 + 255) / 256, 256, 0, stream>>>(solv_Wih, solu_Wih, Wihh);
  conv_x<<<5120, 256, 0, stream>>>(in_solv, Avh, 4096);
  conv_x<<<5120, 256, 0, stream>>>(in_solu, Auh, 4096);

  // ---- layer 0 (scan writes fp16 L0vh/L0uh directly; no fp32 out) ----
  xg_mfma<<<dim3(64, 4), 256, 0, stream>>>(Avh, Auh, Wihh,
      solv_bih, solv_bhh, solu_bih, solu_bhh, xg, 0);
  lstm_scan<0><<<4, 512, 0, stream>>>(solv_Whh, solu_Whh, xg,
      nullptr, nullptr, L0vh, L0uh, 0);

  // ---- layer 1 (scan writes fp32 Hb/Gb + fp16 Hh/Gh) ----
  xg_mfma<<<dim3(64, 4), 256, 0, stream>>>(L0vh, L0uh, Wihh + (size_t)4 * 640 * 320,
      solv_bih, solv_bhh, solu_bih, solu_bhh, xg, 1);
  lstm_scan<1><<<4, 512, 0, stream>>>(solv_Whh, solu_Whh, xg,
      Hb, Gb, Hh, Gh, 1);

  // ---- attention: S once (fp16), rowsum, scale, P/Q combined ----
  conv_t<<<5120, 256, 0, stream>>>(Hb, HhT);
  conv_t<<<5120, 256, 0, stream>>>(Gb, GhT);
  s_gemm<<<dim3(64, 4), 256, 0, stream>>>(Hh, Gh, AH);
  rowsum_k<<<4096, 256, 0, stream>>>(AH, il);
  scale_k<<<8192, 256, 0, stream>>>(AH, il);
  pq_mfma<<<128, 256, 0, stream>>>(AH, GhT, HhT, Pb, Qb);

  // ---- tail ----
  zero_f<<<3, 256, 0, stream>>>(inp, 640);
  reduce_uv<<<32, 320, 0, stream>>>(Hb, Pb, inp, 0);
  reduce_uv<<<32, 320, 0, stream>>>(Gb, Qb, inp, 300);
  fc1_k<<<8, 256, 0, stream>>>(fc1_w, fc1_b, inp, xf);
  fc2_k<<<1, 256, 0, stream>>>(xf, fc2_w, fc2_b, outp);
}

// Round 5
// 6926.916 us; speedup vs baseline: 1.2235x; 1.2235x over previous
//
#include <hip/hip_runtime.h>
#include <hip/hip_fp16.h>
#include <cstddef>

#define T_LEN 4096
#define HID 150
#define G4 600
#define NC 300

typedef __attribute__((ext_vector_type(8))) short bf16x8;      // 8 bf16 = 4 VGPRs
typedef __attribute__((ext_vector_type(8))) _Float16 f16x8;    // 8 fp16 = 4 VGPRs
typedef __attribute__((ext_vector_type(4))) float f32x4;

// raw barrier: waits LDS ops only, leaves global loads/stores in flight
__device__ __forceinline__ void barrier_lgkm() {
  asm volatile("s_waitcnt lgkmcnt(0)\n\ts_barrier" ::: "memory");
}

__device__ __forceinline__ float fsig(float x) {
  return __builtin_amdgcn_rcpf(1.f + __expf(-x));
}
__device__ __forceinline__ float ftanh(float x) {
  float ax = fabsf(x);
  float e = __expf(2.f * ax);
  float t = 1.f - 2.f * __builtin_amdgcn_rcpf(e + 1.f);
  return copysignf(t, x);
}
__device__ __forceinline__ unsigned short f2bf(float f) {  // RNE fp32->bf16
  unsigned u = __builtin_bit_cast(unsigned, f);
  u += 0x7fff + ((u >> 16) & 1);
  return (unsigned short)(u >> 16);
}

// ---------------- LSTM scan via MFMA (r11 EXACT - measured best 1780 cyc/step) -
// LEDGER (cyc/step): r3=1814, r5 af-hoist=1854, r6 gate-permute=2439, r7
// 16-wave=1968, r8 1-barrier=1893, r9 bcast-B+select=2361, r10 gate-major
// 10-wave=2231, r11=1780 BEST, r12 dist-2-prefetch=2234 (vmcnt sched worsened).
// LAWS: (1) two-phase + 8 waves + gate work concentrated on waves 0-2;
// (2) barriers are NOT the bottleneck (r8/r9/r10); (3) per-SIMD pre-barrier
// issue is; (4) xg HBM latency is NOT it either (r12). DO NOT RESTRUCTURE.
template <int W32>
__global__ __launch_bounds__(512, 2) void lstm_scan(
    const float* __restrict__ whh_solv, const float* __restrict__ whh_solu,
    const float* __restrict__ xg_base,
    float* __restrict__ o32v, float* __restrict__ o32u,
    __half* __restrict__ o16v, __half* __restrict__ o16u, int layer)
{
  __shared__ __align__(16) unsigned short h_bf[160];  // bf16 h, zeros beyond 150
  __shared__ __align__(16) float g4[160][4];          // unit-major, gate-minor
  const int c = blockIdx.x;
  const int net = c >> 1, dir = c & 1;
  const float* Whh = (net ? whh_solu : whh_solv) + (size_t)(layer * 2 + dir) * (G4 * HID);
  const float* xg = xg_base + (size_t)c * T_LEN * G4;
  float* out32 = (net ? o32u : o32v) + dir * HID;     // row stride NC (if W32)
  __half* out16 = (net ? o16u : o16v) + dir * HID;    // row stride 320
  const int tid = threadIdx.x;
  const int lane = tid & 63, wv = tid >> 6;
  const int lrow = lane & 15, lq = lane >> 4;  // frag row & k-quad

  // B-fragments, gate-interleaved tiles: T=wv+8j, gt=T&3, uw=T>>2.
  // B[k][lrow] = Whh[gt*150 + (16*uw+lrow)][k]; zero-padded.
  bf16x8 bfr[5][5];  // [j][kk]
#pragma unroll
  for (int j = 0; j < 5; j++) {
    const int T = wv + 8 * j, gt = T & 3, uw = T >> 2;
    const int un = 16 * uw + lrow;
#pragma unroll
    for (int kk = 0; kk < 5; kk++) {
      bf16x8 b;
#pragma unroll
      for (int i = 0; i < 8; i++) {
        const int k = kk * 32 + lq * 8 + i;
        const float v = (un < HID && k < HID) ? Whh[(size_t)(gt * HID + un) * HID + k] : 0.f;
        b[i] = (short)f2bf(v);
      }
      bfr[j][kk] = b;
    }
  }
  if (tid < 160) h_bf[tid] = 0;

  const int t0 = dir ? (T_LEN - 1) : 0;
  const int d16 = dir ? -320 : 320;
  const int d32 = dir ? -NC : NC;
  const int dxg = dir ? -G4 : G4;
  float cst = 0.f;
  float xr0 = 0.f, xr1 = 0.f, xr2 = 0.f, xr3 = 0.f;
  const float* xgp = xg + (size_t)t0 * G4 + tid;   // gate lanes only
  __half* o16p = out16 + (size_t)t0 * 320 + tid;
  float* o32p = out32 + (size_t)t0 * NC + tid;
  if (tid < HID) { xr0 = xgp[0]; xr1 = xgp[HID]; xr2 = xgp[2 * HID]; xr3 = xgp[3 * HID]; }
  barrier_lgkm();

  for (int s = 0; s < T_LEN; s++) {
    // A-frags: row0 = h_bf, rows 1-15 zero -> only lanes with lrow==0 load
    bf16x8 af[5];
#pragma unroll
    for (int kk = 0; kk < 5; kk++) {
      bf16x8 a = {0, 0, 0, 0, 0, 0, 0, 0};
      if (lrow == 0) a = *(const bf16x8*)&h_bf[kk * 32 + lq * 8];
      af[kk] = a;
    }
    f32x4 acc[5];
#pragma unroll
    for (int j = 0; j < 5; j++) acc[j] = (f32x4){0.f, 0.f, 0.f, 0.f};
#pragma unroll
    for (int kk = 0; kk < 5; kk++)
#pragma unroll
      for (int j = 0; j < 5; j++)
        acc[j] = __builtin_amdgcn_mfma_f32_16x16x32_bf16(af[kk], bfr[j][kk], acc[j], 0, 0, 0);
    // D row0 lives in lanes 0-15, reg 0: scatter into unit-major g4.
    // Banks (4*ln+gt)&31: ln vs ln+8 alias -> 2-way conflict = free (m136).
    if (lane < 16) {
#pragma unroll
      for (int j = 0; j < 5; j++) {
        const int T = wv + 8 * j, gt = T & 3, uw = T >> 2;
        g4[16 * uw + lane][gt] = acc[j][0];
      }
    }
    barrier_lgkm();
    if (tid < HID) {
      const f32x4 g = *(const f32x4*)&g4[tid][0];   // ONE b128, coalesced
      float gi = xr0 + g[0];
      float gf = xr1 + g[1];
      float gg = xr2 + g[2];
      float go = xr3 + g[3];
      xgp += dxg;
      if (s + 1 < T_LEN) {  // prefetch next xg row (stays in flight past barrier)
        xr0 = xgp[0]; xr1 = xgp[HID]; xr2 = xgp[2 * HID]; xr3 = xgp[3 * HID];
      }
      const float iv = fsig(gi), fv = fsig(gf), gv = ftanh(gg), ov = fsig(go);
      cst = fv * cst + iv * gv;
      const float hv = ov * ftanh(cst);
      h_bf[tid] = f2bf(hv);      // matvec input rounded; c/h state stays fp32
      *o16p = __float2half(hv);
      o16p += d16;
      if (W32) { *o32p = hv; o32p += d32; }
    }
    barrier_lgkm();
  }
}

// ---------------- fp32 -> fp16 conversion helpers ------------------------------
// Wihh[8][640][320]: slot s = l*4 + net*2 + dir, zero-padded rows/cols
__global__ void conv_w(const float* __restrict__ wv, const float* __restrict__ wu,
                       __half* __restrict__ dst)
{
  const int gid = blockIdx.x * 256 + threadIdx.x;
  if (gid >= 8 * 640 * 320) return;
  const int k = gid % 320, j = (gid / 320) % 640, s = gid / (320 * 640);
  const int l = s >> 2, net = (s >> 1) & 1, dir = s & 1;
  float v = 0.f;
  if (j < G4 && k < NC) {
    const float* src = (net ? wu : wv) + (size_t)(l * 2 + dir) * (G4 * NC);
    v = src[(size_t)j * NC + k];
  }
  dst[gid] = __float2half(v);
}

// X fp32 [4096][300] -> Xh fp16 [4096][320] zero-padded; y selects solv/solu
__global__ void conv_x2(const float* __restrict__ s0, const float* __restrict__ s1,
                        __half* __restrict__ d0, __half* __restrict__ d1)
{
  const int gid = blockIdx.x * 256 + threadIdx.x;
  if (gid >= 4096 * 320) return;
  const float* src = blockIdx.y ? s1 : s0;
  __half* dst = blockIdx.y ? d1 : d0;
  const int k = gid % 320, m = gid / 320;
  dst[gid] = __float2half(k < NC ? src[(size_t)m * NC + k] : 0.f);
}

// X fp32 [4096][300] -> XT fp16 [320][4096] (rows >= 300 zeroed); y selects H/G
__global__ void conv_t2(const float* __restrict__ s0, const float* __restrict__ s1,
                        __half* __restrict__ d0, __half* __restrict__ d1)
{
  const int gid = blockIdx.x * 256 + threadIdx.x;
  if (gid >= 320 * 4096) return;
  const float* src = blockIdx.y ? s1 : s0;
  __half* dst = blockIdx.y ? d1 : d0;
  const int m = gid % 4096, f = gid / 4096;
  dst[gid] = __float2half(f < NC ? src[(size_t)m * NC + f] : 0.f);
}

__global__ void zero_f(float* __restrict__ p, int n) {
  const int i = blockIdx.x * 256 + threadIdx.x;
  if (i < n) p[i] = 0.f;
}

// ---------------- xg = X @ Wih^T + b via fp16 MFMA -----------------------------
// grid (64 m-blocks, 4 chains), block 256 (4 waves, 16 rows each). N=640, K=320.
__global__ __launch_bounds__(256) void xg_mfma(
    const __half* __restrict__ Av, const __half* __restrict__ Au,
    const __half* __restrict__ W,   // Wihh + layer*4*640*320
    const float* __restrict__ bihv, const float* __restrict__ bhhv,
    const float* __restrict__ bihu, const float* __restrict__ bhhu,
    float* __restrict__ xg, int layer)
{
  const int tid = threadIdx.x;
  const int lane = tid & 63, wv = tid >> 6;
  const int ln = lane & 15, q = lane >> 4;
  const int chain = blockIdx.y;
  const __half* A = (chain >= 2) ? Au : Av;
  const __half* Wc = W + (size_t)chain * 640 * 320;
  const float* bi = ((chain >= 2) ? bihu : bihv) + (size_t)(layer * 2 + (chain & 1)) * G4;
  const float* bh = ((chain >= 2) ? bhhu : bhhv) + (size_t)(layer * 2 + (chain & 1)) * G4;
  float* C = xg + (size_t)chain * T_LEN * G4;
  const int m0 = blockIdx.x * 64 + wv * 16;
  const __half* Arow = A + (size_t)(m0 + ln) * 320;

  for (int nc = 0; nc < 4; nc++) {       // 4 chunks x 160 cols
    f32x4 acc[10];
#pragma unroll
    for (int j = 0; j < 10; j++) acc[j] = (f32x4){0.f, 0.f, 0.f, 0.f};
    for (int kk = 0; kk < 10; kk++) {
      const f16x8 afr = *(const f16x8*)(Arow + kk * 32 + q * 8);
#pragma unroll
      for (int j = 0; j < 10; j++) {
        const int n = nc * 160 + j * 16 + ln;
        const f16x8 bfr = *(const f16x8*)(Wc + (size_t)n * 320 + kk * 32 + q * 8);
        acc[j] = __builtin_amdgcn_mfma_f32_16x16x32_f16(afr, bfr, acc[j], 0, 0, 0);
      }
    }
#pragma unroll
    for (int j = 0; j < 10; j++) {
      const int n = nc * 160 + j * 16 + ln;
      if (n < G4) {
        const float bias = bi[n] + bh[n];
#pragma unroll
        for (int r = 0; r < 4; r++)
          C[(size_t)(m0 + q * 4 + r) * G4 + n] = acc[j][r] + bias;
      }
    }
  }
}

// ------- S GEMM: AH[m][n] = fp16(Hh[m] . Gh[n]), raw scores (no exp) -----------
// grid (64 m-blocks, 4 n-quadrants), block 256. Softmax shift/normalization
// happens later on the ROUNDED values (self-consistent).
__global__ __launch_bounds__(256) void s_gemm(
    const __half* __restrict__ Hh, const __half* __restrict__ Gh,
    __half* __restrict__ AH)
{
  const int tid = threadIdx.x;
  const int lane = tid & 63, wv = tid >> 6;
  const int ln = lane & 15, q = lane >> 4;
  const int m0 = blockIdx.x * 64 + wv * 16;
  const __half* Arow = Hh + (size_t)(m0 + ln) * 320;
  f16x8 afr[10];
#pragma unroll
  for (int kk = 0; kk < 10; kk++) afr[kk] = *(const f16x8*)(Arow + kk * 32 + q * 8);
  const int nt0 = blockIdx.y * 64;
  for (int nt = 0; nt < 64; nt++) {
    const int n = 16 * (nt0 + nt) + ln;
    const __half* Brow = Gh + (size_t)n * 320;
    f32x4 acc = (f32x4){0.f, 0.f, 0.f, 0.f};
#pragma unroll
    for (int kk = 0; kk < 10; kk++) {
      const f16x8 bfr = *(const f16x8*)(Brow + kk * 32 + q * 8);
      acc = __builtin_amdgcn_mfma_f32_16x16x32_f16(afr[kk], bfr, acc, 0, 0, 0);
    }
#pragma unroll
    for (int r = 0; r < 4; r++)
      AH[(size_t)(m0 + q * 4 + r) * 4096 + n] = __float2half(acc[r]);
  }
}

// ------- fused softmax: AH[m][:] = fp16( exp(S-30) / sum exp(S-30) ) -----------
// One block per row; the 16 exp values per thread stay in REGISTERS between
// the sum pass and the scale pass -> one HBM read + one write (was 3 passes:
// rowsum read 32MB + scale read/write 64MB). Identical arithmetic & rounding.
__global__ __launch_bounds__(256) void softmax_k(__half* __restrict__ AH)
{
  const int m = blockIdx.x, tid = threadIdx.x;
  __half* row = AH + (size_t)m * 4096;
  float e[16];
  float s = 0.f;
#pragma unroll
  for (int c = 0; c < 2; c++) {
    const f16x8 v = *(const f16x8*)(row + c * 2048 + tid * 8);
#pragma unroll
    for (int j = 0; j < 8; j++) {
      const float ev = __expf(fminf((float)v[j] - 30.f, 80.f));
      e[c * 8 + j] = ev;
      s += ev;
    }
  }
#pragma unroll
  for (int off = 32; off > 0; off >>= 1) s += __shfl_down(s, off);
  __shared__ float red[4];
  if ((tid & 63) == 0) red[tid >> 6] = s;
  __syncthreads();
  const float ilm = 1.f / (red[0] + red[1] + red[2] + red[3]);
#pragma unroll
  for (int c = 0; c < 2; c++) {
    f16x8 v;
#pragma unroll
    for (int j = 0; j < 8; j++) v[j] = (_Float16)(e[c * 8 + j] * ilm);
    *(f16x8*)(row + c * 2048 + tid * 8) = v;
  }
}

// ------- P = AH @ GhT' and Q = AH^T @ HhT' in ONE dispatch (128 blocks) --------
__global__ __launch_bounds__(256) void pq_mfma(
    const __half* __restrict__ AH, const __half* __restrict__ GhT,
    const __half* __restrict__ HhT,
    float* __restrict__ Pb, float* __restrict__ Qb)
{
  __shared__ __align__(16) _Float16 Ats[64][72];  // qt staging, pitch 144 B
  const int tid = threadIdx.x;
  const int lane = tid & 63, wv = tid >> 6;
  const int ln = lane & 15, q = lane >> 4;

  if (blockIdx.x < 64) {
    // ---- P part: M=4096 rows of AH, N=320(store 300), K=4096 ----
    const int m0 = blockIdx.x * 64 + wv * 16;
    const __half* Arow = AH + (size_t)(m0 + ln) * 4096;
    for (int nc = 0; nc < 2; nc++) {
      f32x4 acc[10];
#pragma unroll
      for (int j = 0; j < 10; j++) acc[j] = (f32x4){0.f, 0.f, 0.f, 0.f};
      for (int kk = 0; kk < 128; kk++) {
        const f16x8 afr = *(const f16x8*)(Arow + kk * 32 + q * 8);
#pragma unroll
        for (int j = 0; j < 10; j++) {
          const int n = nc * 160 + j * 16 + ln;
          const f16x8 bfr = *(const f16x8*)(GhT + (size_t)n * 4096 + kk * 32 + q * 8);
          acc[j] = __builtin_amdgcn_mfma_f32_16x16x32_f16(afr, bfr, acc[j], 0, 0, 0);
        }
      }
#pragma unroll
      for (int j = 0; j < 10; j++) {
        const int n = nc * 160 + j * 16 + ln;
        if (n < NC) {
#pragma unroll
          for (int r = 0; r < 4; r++)
            Pb[(size_t)(m0 + q * 4 + r) * NC + n] = acc[j][r];
        }
      }
    }
  } else {
    // ---- Q part: Q[j][f] = sum_i a[i][j] H[i][f]; a transposed via LDS ----
    const int j0 = (blockIdx.x - 64) * 64;
    f32x4 acc[20];
#pragma unroll
    for (int j = 0; j < 20; j++) acc[j] = (f32x4){0.f, 0.f, 0.f, 0.f};
    const int il8 = tid >> 2, j8 = (tid & 3) * 16;  // staging role
    for (int ic = 0; ic < 4096; ic += 64) {
      __syncthreads();
      {
        const __half* src = AH + (size_t)(ic + il8) * 4096 + j0 + j8;
        const f16x8 v0 = *(const f16x8*)src;
        const f16x8 v1 = *(const f16x8*)(src + 8);
#pragma unroll
        for (int jj = 0; jj < 8; jj++) Ats[j8 + jj][il8] = v0[jj];
#pragma unroll
        for (int jj = 0; jj < 8; jj++) Ats[j8 + 8 + jj][il8] = v1[jj];
      }
      __syncthreads();
#pragma unroll
      for (int s = 0; s < 2; s++) {
        const f16x8 afr = *(const f16x8*)&Ats[wv * 16 + ln][s * 32 + q * 8];
        const __half* bbase = HhT + ic + s * 32 + q * 8;
#pragma unroll
        for (int j = 0; j < 20; j++) {
          const f16x8 bfr = *(const f16x8*)(bbase + (size_t)(j * 16 + ln) * 4096);
          acc[j] = __builtin_amdgcn_mfma_f32_16x16x32_f16(afr, bfr, acc[j], 0, 0, 0);
        }
      }
    }
#pragma unroll
    for (int j = 0; j < 20; j++) {
      const int f = j * 16 + ln;
      if (f < NC) {
#pragma unroll
        for (int r = 0; r < 4; r++)
          Qb[(size_t)(j0 + wv * 16 + q * 4 + r) * NC + f] = acc[j][r];
      }
    }
  }
}

// ---------------- tail ---------------------------------------------------------
// y=0: max(Hb,Pb) col-sums into inp[0..299]; y=1: max(Gb,Qb) into inp[300..599]
__global__ void reduce_uv2(const float* __restrict__ Hb, const float* __restrict__ Pb,
                           const float* __restrict__ Gb, const float* __restrict__ Qb,
                           float* __restrict__ inp)
{
  const int j = threadIdx.x;
  if (j >= NC) return;
  const float* X = blockIdx.y ? Gb : Hb;
  const float* Yp = blockIdx.y ? Qb : Pb;
  const int off = blockIdx.y ? NC : 0;
  const int r0 = blockIdx.x * 128;
  float s = 0.f;
  for (int r = r0; r < r0 + 128; r++)
    s += fmaxf(X[(size_t)r * NC + j], Yp[(size_t)r * NC + j]);
  atomicAdd(&inp[off + j], s);
}

// wave-per-row: coalesced w1 reads (old thread-per-row was stride-2400B,
// 8 blocks, latency-bound). 500 blocks x 4 waves = 2000 rows.
__global__ __launch_bounds__(256) void fc1_k(
    const float* __restrict__ w1, const float* __restrict__ b1,
    const float* __restrict__ inp, float* __restrict__ x)
{
  const int r = blockIdx.x * 4 + (threadIdx.x >> 6);
  const int lane = threadIdx.x & 63;
  const float* wr = w1 + (size_t)r * 600;
  float s = 0.f;
  for (int k = lane; k < 600; k += 64) s += wr[k] * inp[k];
#pragma unroll
  for (int off = 32; off > 0; off >>= 1) s += __shfl_down(s, off);
  if (lane == 0) x[r] = fmaxf(s + b1[r], 0.f);
}

__global__ void fc2_k(const float* __restrict__ x, const float* __restrict__ w2,
                      const float* __restrict__ b2, float* __restrict__ outp)
{
  const int tid = threadIdx.x;
  float s = 0.f;
  for (int i = tid; i < 2000; i += 256) s += x[i] * w2[i];
#pragma unroll
  for (int off = 32; off > 0; off >>= 1) s += __shfl_down(s, off);
  __shared__ float red[4];
  if ((tid & 63) == 0) red[tid >> 6] = s;
  __syncthreads();
  if (tid == 0) outp[0] = red[0] + red[1] + red[2] + red[3] + b2[0];
}

// ---------------- launch --------------------------------------------------------
extern "C" void kernel_launch(void* const* d_in, const int* in_sizes, int n_in,
                              void* d_out, int out_size, void* d_ws, size_t ws_size,
                              hipStream_t stream)
{
  const float* in_solv  = (const float*)d_in[0];
  const float* in_solu  = (const float*)d_in[1];
  const float* solv_Wih = (const float*)d_in[2];
  const float* solv_Whh = (const float*)d_in[3];
  const float* solv_bih = (const float*)d_in[4];
  const float* solv_bhh = (const float*)d_in[5];
  const float* solu_Wih = (const float*)d_in[6];
  const float* solu_Whh = (const float*)d_in[7];
  const float* solu_bih = (const float*)d_in[8];
  const float* solu_bhh = (const float*)d_in[9];
  const float* fc1_w = (const float*)d_in[10];
  const float* fc1_b = (const float*)d_in[11];
  const float* fc2_w = (const float*)d_in[12];
  const float* fc2_b = (const float*)d_in[13];
  float* outp = (float*)d_out;
  float* ws = (float*)d_ws;

  // ---- workspace layout (float offsets); peak 16,067,200 fl ----
  constexpr size_t off_P   = 0;
  constexpr size_t off_Q   = 1228800;
  constexpr size_t off_inp = 2457600;   // 640
  constexpr size_t off_x   = 2458240;   // 2048
  constexpr size_t off_xg  = 2468480;
  constexpr size_t off_L0  = off_xg + (size_t)4 * 2457600;   // 12,298,880
  constexpr size_t off_HG  = off_L0 + 1310720;               // 13,609,600

  float*  xg   = ws + off_xg;
  float*  Hb   = ws + off_HG;
  float*  Gb   = Hb + 1228800;
  float*  Pb   = ws + off_P;
  float*  Qb   = ws + off_Q;
  float*  inp  = ws + off_inp;
  float*  xf   = ws + off_x;
  __half* Wihh = (__half*)(ws + off_P);
  __half* Avh  = (__half*)(ws + off_L0);
  __half* Auh  = Avh + 4096 * 320;
  __half* L0vh = (__half*)(ws + off_HG);
  __half* L0uh = L0vh + 4096 * 320;
  __half* Hh   = (__half*)(ws + off_L0);   // reuses Avh/Auh space (dead)
  __half* Gh   = Hh + 4096 * 320;
  __half* AH   = (__half*)(ws + off_xg);   // after scans (xg dead)
  __half* HhT  = AH + (size_t)4096 * 4096;
  __half* GhT  = HhT + 320 * 4096;

  // ---- prep: zero L0vh/L0uh pads, convert weights + inputs to fp16 ----
  zero_f<<<5120, 256, 0, stream>>>(ws + off_HG, 1310720);
  conv_w<<<(8 * 640 * 320 + 255) / 256, 256, 0, stream>>>(solv_Wih, solu_Wih, Wihh);
  conv_x2<<<dim3(5120, 2), 256, 0, stream>>>(in_solv, in_solu, Avh, Auh);

  // ---- layer 0 (scan writes fp16 L0vh/L0uh directly; no fp32 out) ----
  xg_mfma<<<dim3(64, 4), 256, 0, stream>>>(Avh, Auh, Wihh,
      solv_bih, solv_bhh, solu_bih, solu_bhh, xg, 0);
  lstm_scan<0><<<4, 512, 0, stream>>>(solv_Whh, solu_Whh, xg,
      nullptr, nullptr, L0vh, L0uh, 0);

  // ---- layer 1 (scan writes fp32 Hb/Gb + fp16 Hh/Gh) ----
  xg_mfma<<<dim3(64, 4), 256, 0, stream>>>(L0vh, L0uh, Wihh + (size_t)4 * 640 * 320,
      solv_bih, solv_bhh, solu_bih, solu_bhh, xg, 1);
  lstm_scan<1><<<4, 512, 0, stream>>>(solv_Whh, solu_Whh, xg,
      Hb, Gb, Hh, Gh, 1);

  // ---- attention: S once (fp16), fused softmax, P/Q combined ----
  conv_t2<<<dim3(5120, 2), 256, 0, stream>>>(Hb, Gb, HhT, GhT);
  s_gemm<<<dim3(64, 4), 256, 0, stream>>>(Hh, Gh, AH);
  softmax_k<<<4096, 256, 0, stream>>>(AH);
  pq_mfma<<<128, 256, 0, stream>>>(AH, GhT, HhT, Pb, Qb);

  // ---- tail ----
  zero_f<<<3, 256, 0, stream>>>(inp, 640);
  reduce_uv2<<<dim3(32, 2), 320, 0, stream>>>(Hb, Pb, Gb, Qb, inp);
  fc1_k<<<500, 256, 0, stream>>>(fc1_w, fc1_b, inp, xf);
  fc2_k<<<1, 256, 0, stream>>>(xf, fc2_w, fc2_b, outp);
}